// Round 2
// baseline (125.719 us; speedup 1.0000x reference)
//
#include <hip/hip_runtime.h>
#include <hip/hip_cooperative_groups.h>
#include <math.h>

namespace cg = cooperative_groups;

// Problem dims (fixed by setup_inputs): B=64 samples, N=512 spins/flips, H=2048 hidden
constexpr int NB = 64;
constexpr int NN = 512;
constexpr int NH = 2048;
constexpr float LN2 = 0.6931471805599453f;

// Workspace: Tt4[h/4][b][4] = tanh(theta) packed 4-h per float4 slot (2048*64 floats)

// ===== Fused cooperative kernel: 256 blocks x 512 thr (1 block/CU, 8 waves/CU).
// Phase 1: theta GEMM + tanh -> Tt4 (32 h-tiles x 8 b-tiles of 8).
// grid.sync()
// Phase 2: block owns flips k0=2*bid, k0+1; 8 waves split h 8x256; on-the-fly tanh(2W).
__global__ __launch_bounds__(512) void k_fused(const float* __restrict__ W,
                                               const float* __restrict__ x,
                                               const float* __restrict__ bvec,
                                               const float* __restrict__ a,
                                               const float* __restrict__ Oxy,
                                               float* __restrict__ Tt4,
                                               float* __restrict__ out) {
    __shared__ float sm[6144];             // 24 KB; phase1: xs(stride12)->red; phase2: t2s+red
    int tid = threadIdx.x;
    int bid = blockIdx.x;

    // ================= Phase 1: theta GEMM =================
    {
        int ht  = bid & 31;                // h-tile of 64
        int btb = bid >> 5;                // b-tile of 8
        // transpose x slice into LDS: xs[n][j], row stride 12 floats (48B, 16B-aligned)
        {
            int j = tid >> 6, c = tid & 63;                // 8 rows x 64 cols
            const float4* xr = (const float4*)(x + (size_t)(btb * 8 + j) * NN);
#pragma unroll
            for (int i = 0; i < 2; i++) {
                float4 v = xr[c + i * 64];
                int n0 = (c + i * 64) * 4;
                sm[(n0 + 0) * 12 + j] = v.x;
                sm[(n0 + 1) * 12 + j] = v.y;
                sm[(n0 + 2) * 12 + j] = v.z;
                sm[(n0 + 3) * 12 + j] = v.w;
            }
        }
        __syncthreads();
        int hl = tid & 63, ns = tid >> 6;  // 8 n-segments of 64
        float acc[8];
#pragma unroll
        for (int q = 0; q < 8; q++) acc[q] = 0.f;
        const float* wp = W + ht * 64 + hl;
#pragma unroll 4
        for (int n = ns * 64; n < ns * 64 + 64; n++) {
            float w = wp[(size_t)n * NH];                  // coalesced 256B/wave
            const float4* xv = (const float4*)(sm + n * 12);   // wave-uniform broadcast
            float4 a0 = xv[0], a1 = xv[1];
            acc[0] = fmaf(a0.x, w, acc[0]); acc[1] = fmaf(a0.y, w, acc[1]);
            acc[2] = fmaf(a0.z, w, acc[2]); acc[3] = fmaf(a0.w, w, acc[3]);
            acc[4] = fmaf(a1.x, w, acc[4]); acc[5] = fmaf(a1.y, w, acc[5]);
            acc[6] = fmaf(a1.z, w, acc[6]); acc[7] = fmaf(a1.w, w, acc[7]);
        }
        __syncthreads();                   // xs dead; reuse sm as red[ns][hl][8] = 16KB
        float4* r4 = (float4*)sm;
        r4[ns * 128 + hl * 2 + 0] = make_float4(acc[0], acc[1], acc[2], acc[3]);
        r4[ns * 128 + hl * 2 + 1] = make_float4(acc[4], acc[5], acc[6], acc[7]);
        __syncthreads();
        // 512 outputs: tid -> (hl2 in [0,64), j2 in [0,8))
        int hl2 = tid >> 3, j2 = tid & 7;
        float th = bvec[ht * 64 + hl2];
#pragma unroll
        for (int n2 = 0; n2 < 8; n2++) th += sm[n2 * 512 + hl2 * 8 + j2];
        float ay = fabsf(th);
        float e  = __expf(-2.0f * ay);
        float T  = copysignf((1.0f - e) / (1.0f + e), th);
        int h = ht * 64 + hl2, b = btb * 8 + j2;
        Tt4[(size_t)(h >> 2) * 256 + b * 4 + (h & 3)] = T;
        if (bid == 0 && tid < NB) out[tid] = 0.f;   // zero out before phase-2 atomics
    }
    cg::this_grid().sync();

    // ================= Phase 2: flip accumulation =================
    {
        float* t2s0 = sm;                  // [NH] tanh(2W[k0][:])
        float* t2s1 = sm + NH;             // [NH] tanh(2W[k0+1][:])
        float* red  = sm + 2 * NH;         // [16*NB] cross-wave reduce
        int lane = tid & 63, wv = tid >> 6;    // lane<->b, 8 waves split h
        int k0 = __builtin_amdgcn_readfirstlane(blockIdx.x * 2);
        int hb = wv * 256;                 // this wave's h-range [hb, hb+256)

        // ---- prep: tanh(2W) into LDS planes + per-wave lncosh partials ----
        const float2* w0 = (const float2*)(W + (size_t)k0 * NH + hb);
        const float2* w1 = (const float2*)(W + (size_t)(k0 + 1) * NH + hb);
        float lc0 = 0.f, lc1 = 0.f;
#pragma unroll
        for (int i = 0; i < 2; i++) {
            float2 wa = w0[lane + i * 64];
            float2 wb = w1[lane + i * 64];
            float in[4] = {wa.x, wa.y, wb.x, wb.y};
            float t[4];
#pragma unroll
            for (int q = 0; q < 4; q++) {
                float y  = 2.0f * in[q];
                float ay = fabsf(y);
                float e  = __expf(-2.0f * ay);
                t[q] = copysignf((1.0f - e) / (1.0f + e), y);
                float l = ay + __logf(1.0f + e) - LN2;     // lncosh(y)
                if (q < 2) lc0 += l; else lc1 += l;
            }
            int h2 = hb + (lane + i * 64) * 2;
            *(float2*)&t2s0[h2] = make_float2(t[0], t[1]);
            *(float2*)&t2s1[h2] = make_float2(t[2], t[3]);
        }
#pragma unroll
        for (int off = 32; off > 0; off >>= 1) {           // 64-lane butterfly
            lc0 += __shfl_xor(lc0, off);
            lc1 += __shfl_xor(lc1, off);
        }
        float ms0 = -x[(size_t)lane * NN + k0];            // -x[b][k0], L2 gather
        float ms1 = -x[(size_t)lane * NN + k0 + 1];
        __syncthreads();                   // insurance; t2s regions are wave-private

        // ---- hot loop: float4 Tt loads + b128 LDS broadcasts, 4 h per step ----
        float lp0 = lc0, lp1 = lc1;        // fold lncosh partials into log-sum
        const float* tp = Tt4 + lane * 4;
        for (int h0 = hb; h0 < hb + 256; h0 += 32) {
            float p0 = 1.f, p1 = 1.f;
#pragma unroll
            for (int hh = 0; hh < 32; hh += 4) {
                int h = h0 + hh;
                float4 T  = *(const float4*)(tp + (size_t)h * 64);   // dwordx4, 1KB/wave
                float4 t0 = *(const float4*)&t2s0[h];                // ds_read_b128 bcast
                float4 t1 = *(const float4*)&t2s1[h];
                p0 *= fmaf(t0.x * T.x, ms0, 1.f);          // 1 - s*T*tanh(2W)
                p0 *= fmaf(t0.y * T.y, ms0, 1.f);
                p0 *= fmaf(t0.z * T.z, ms0, 1.f);
                p0 *= fmaf(t0.w * T.w, ms0, 1.f);
                p1 *= fmaf(t1.x * T.x, ms1, 1.f);
                p1 *= fmaf(t1.y * T.y, ms1, 1.f);
                p1 *= fmaf(t1.z * T.z, ms1, 1.f);
                p1 *= fmaf(t1.w * T.w, ms1, 1.f);
            }
            lp0 += __logf(p0);             // |ln u| small -> 32-chunk product safe
            lp1 += __logf(p1);
        }
        red[(wv * 2 + 0) * NB + lane] = lp0;
        red[(wv * 2 + 1) * NB + lane] = lp1;
        __syncthreads();
        if (tid < NB) {                    // wave 0 finalizes; lane = b = tid
            float d0 = 2.0f * ms0 * a[k0];             // -2 x a = +2 ms a
            float d1 = 2.0f * ms1 * a[k0 + 1];
#pragma unroll
            for (int w2 = 0; w2 < 8; w2++) {
                d0 += red[(w2 * 2 + 0) * NB + tid];
                d1 += red[(w2 * 2 + 1) * NB + tid];
            }
            float c = Oxy[k0] * __expf(d0) + Oxy[k0 + 1] * __expf(d1);
            atomicAdd(&out[tid], c);       // 256 adds per address, device-scope
        }
    }
}

extern "C" void kernel_launch(void* const* d_in, const int* in_sizes, int n_in,
                              void* d_out, int out_size, void* d_ws, size_t ws_size,
                              hipStream_t stream) {
    const float* x    = (const float*)d_in[0];
    const float* W    = (const float*)d_in[1];
    const float* bvec = (const float*)d_in[2];
    const float* a    = (const float*)d_in[3];
    const float* Oxy  = (const float*)d_in[4];
    float* out = (float*)d_out;
    float* Tt4 = (float*)d_ws;

    void* args[] = {(void*)&W, (void*)&x, (void*)&bvec, (void*)&a, (void*)&Oxy,
                    (void*)&Tt4, (void*)&out};
    hipLaunchCooperativeKernel((void*)k_fused, dim3(256), dim3(512), args, 0, stream);
}

// Round 3
// 86.930 us; speedup vs baseline: 1.4462x; 1.4462x over previous
//
#include <hip/hip_runtime.h>
#include <math.h>

// Problem dims (fixed by setup_inputs): B=64 samples, N=512 spins/flips, H=2048 hidden
constexpr int NB = 64;
constexpr int NN = 512;
constexpr int NH = 2048;
constexpr float LN2 = 0.6931471805599453f;

// Workspace: Tt4[h/4][b][4] = tanh(theta) packed 4-h per float4 slot (2048*64 floats)

// ===== D1: theta GEMM + tanh -> Tt4. 256 blocks x 512 thr (32 h-tiles x 8 b-tiles of 8).
__global__ __launch_bounds__(512) void k_theta(const float* __restrict__ W,
                                               const float* __restrict__ x,
                                               const float* __restrict__ bvec,
                                               float* __restrict__ Tt4,
                                               float* __restrict__ out) {
    __shared__ float sm[6144];             // 24 KB; xs(stride12) then red
    int tid = threadIdx.x;
    int bid = blockIdx.x;
    int ht  = bid & 31;                    // h-tile of 64
    int btb = bid >> 5;                    // b-tile of 8
    // transpose x slice into LDS: xs[n][j], row stride 12 floats (48B, 16B-aligned)
    {
        int j = tid >> 6, c = tid & 63;    // 8 rows x 64 cols
        const float4* xr = (const float4*)(x + (size_t)(btb * 8 + j) * NN);
#pragma unroll
        for (int i = 0; i < 2; i++) {
            float4 v = xr[c + i * 64];
            int n0 = (c + i * 64) * 4;
            sm[(n0 + 0) * 12 + j] = v.x;
            sm[(n0 + 1) * 12 + j] = v.y;
            sm[(n0 + 2) * 12 + j] = v.z;
            sm[(n0 + 3) * 12 + j] = v.w;
        }
    }
    __syncthreads();
    int hl = tid & 63, ns = tid >> 6;      // 8 n-segments of 64
    float acc[8];
#pragma unroll
    for (int q = 0; q < 8; q++) acc[q] = 0.f;
    const float* wp = W + ht * 64 + hl;
#pragma unroll 4
    for (int n = ns * 64; n < ns * 64 + 64; n++) {
        float w = wp[(size_t)n * NH];      // coalesced 256B/wave
        const float4* xv = (const float4*)(sm + n * 12);   // wave-uniform broadcast
        float4 a0 = xv[0], a1 = xv[1];
        acc[0] = fmaf(a0.x, w, acc[0]); acc[1] = fmaf(a0.y, w, acc[1]);
        acc[2] = fmaf(a0.z, w, acc[2]); acc[3] = fmaf(a0.w, w, acc[3]);
        acc[4] = fmaf(a1.x, w, acc[4]); acc[5] = fmaf(a1.y, w, acc[5]);
        acc[6] = fmaf(a1.z, w, acc[6]); acc[7] = fmaf(a1.w, w, acc[7]);
    }
    __syncthreads();                       // xs dead; reuse sm as red[ns][hl][8] = 16KB
    float4* r4 = (float4*)sm;
    r4[ns * 128 + hl * 2 + 0] = make_float4(acc[0], acc[1], acc[2], acc[3]);
    r4[ns * 128 + hl * 2 + 1] = make_float4(acc[4], acc[5], acc[6], acc[7]);
    __syncthreads();
    // 512 outputs: tid -> (hl2 in [0,64), j2 in [0,8))
    int hl2 = tid >> 3, j2 = tid & 7;
    float th = bvec[ht * 64 + hl2];
#pragma unroll
    for (int n2 = 0; n2 < 8; n2++) th += sm[n2 * 512 + hl2 * 8 + j2];
    float ay = fabsf(th);
    float e  = __expf(-2.0f * ay);
    float T  = copysignf((1.0f - e) / (1.0f + e), th);
    int h = ht * 64 + hl2, b = btb * 8 + j2;
    Tt4[(size_t)(h >> 2) * 256 + b * 4 + (h & 3)] = T;
    if (bid == 0 && tid < NB) out[tid] = 0.f;   // zero out before D2's atomics
}

// ===== D2: 256 blocks x 512 thr; block owns flips k0=2*bid, k0+1; 8 waves split h 8x256;
// tanh(2W) + lncosh(2W) on the fly (no t2/LC round-trip).
__global__ __launch_bounds__(512) void k_main(const float* __restrict__ W,
                                              const float* __restrict__ Tt4,
                                              const float* __restrict__ x,
                                              const float* __restrict__ a,
                                              const float* __restrict__ Oxy,
                                              float* __restrict__ out) {
    __shared__ float t2s0[NH];             // tanh(2W[k0][:])    8 KB
    __shared__ float t2s1[NH];             // tanh(2W[k0+1][:])  8 KB
    __shared__ float red[16 * NB];         // 4 KB cross-wave reduce
    int tid = threadIdx.x;
    int lane = tid & 63, wv = tid >> 6;    // lane<->b, 8 waves split h
    int k0 = __builtin_amdgcn_readfirstlane(blockIdx.x * 2);
    int hb = wv * 256;                     // this wave's h-range [hb, hb+256)

    // ---- prep: tanh(2W) into LDS planes + per-wave lncosh partials ----
    const float2* w0 = (const float2*)(W + (size_t)k0 * NH + hb);
    const float2* w1 = (const float2*)(W + (size_t)(k0 + 1) * NH + hb);
    float lc0 = 0.f, lc1 = 0.f;
#pragma unroll
    for (int i = 0; i < 2; i++) {
        float2 wa = w0[lane + i * 64];
        float2 wb = w1[lane + i * 64];
        float in[4] = {wa.x, wa.y, wb.x, wb.y};
        float t[4];
#pragma unroll
        for (int q = 0; q < 4; q++) {
            float y  = 2.0f * in[q];
            float ay = fabsf(y);
            float e  = __expf(-2.0f * ay);
            t[q] = copysignf((1.0f - e) / (1.0f + e), y);
            float l = ay + __logf(1.0f + e) - LN2;     // lncosh(y)
            if (q < 2) lc0 += l; else lc1 += l;
        }
        int h2 = hb + (lane + i * 64) * 2;
        *(float2*)&t2s0[h2] = make_float2(t[0], t[1]);
        *(float2*)&t2s1[h2] = make_float2(t[2], t[3]);
    }
#pragma unroll
    for (int off = 32; off > 0; off >>= 1) {           // 64-lane butterfly
        lc0 += __shfl_xor(lc0, off);
        lc1 += __shfl_xor(lc1, off);
    }
    float ms0 = -x[(size_t)lane * NN + k0];            // -x[b][k0], L2 gather
    float ms1 = -x[(size_t)lane * NN + k0 + 1];
    __syncthreads();                       // insurance; t2s regions are wave-private

    // ---- hot loop: float4 Tt loads + b128 LDS broadcasts, 4 h per step ----
    float lp0 = lc0, lp1 = lc1;            // fold lncosh partials into log-sum
    const float* tp = Tt4 + lane * 4;
    for (int h0 = hb; h0 < hb + 256; h0 += 32) {
        float p0 = 1.f, p1 = 1.f;
#pragma unroll
        for (int hh = 0; hh < 32; hh += 4) {
            int h = h0 + hh;
            float4 T  = *(const float4*)(tp + (size_t)h * 64);   // dwordx4, 1KB/wave
            float4 t0 = *(const float4*)&t2s0[h];                // ds_read_b128 bcast
            float4 t1 = *(const float4*)&t2s1[h];
            p0 *= fmaf(t0.x * T.x, ms0, 1.f);          // 1 - s*T*tanh(2W)
            p0 *= fmaf(t0.y * T.y, ms0, 1.f);
            p0 *= fmaf(t0.z * T.z, ms0, 1.f);
            p0 *= fmaf(t0.w * T.w, ms0, 1.f);
            p1 *= fmaf(t1.x * T.x, ms1, 1.f);
            p1 *= fmaf(t1.y * T.y, ms1, 1.f);
            p1 *= fmaf(t1.z * T.z, ms1, 1.f);
            p1 *= fmaf(t1.w * T.w, ms1, 1.f);
        }
        lp0 += __logf(p0);                 // |ln u| small -> 32-chunk product safe
        lp1 += __logf(p1);
    }
    red[(wv * 2 + 0) * NB + lane] = lp0;
    red[(wv * 2 + 1) * NB + lane] = lp1;
    __syncthreads();
    if (tid < NB) {                        // wave 0 finalizes; lane = b = tid
        float d0 = 2.0f * ms0 * a[k0];     // -2 x a = +2 ms a
        float d1 = 2.0f * ms1 * a[k0 + 1];
#pragma unroll
        for (int w2 = 0; w2 < 8; w2++) {
            d0 += red[(w2 * 2 + 0) * NB + tid];
            d1 += red[(w2 * 2 + 1) * NB + tid];
        }
        float c = Oxy[k0] * __expf(d0) + Oxy[k0 + 1] * __expf(d1);
        atomicAdd(&out[tid], c);           // 256 adds per address, device-scope
    }
}

extern "C" void kernel_launch(void* const* d_in, const int* in_sizes, int n_in,
                              void* d_out, int out_size, void* d_ws, size_t ws_size,
                              hipStream_t stream) {
    const float* x    = (const float*)d_in[0];
    const float* W    = (const float*)d_in[1];
    const float* bvec = (const float*)d_in[2];
    const float* a    = (const float*)d_in[3];
    const float* Oxy  = (const float*)d_in[4];
    float* out = (float*)d_out;
    float* Tt4 = (float*)d_ws;

    k_theta<<<256, 512, 0, stream>>>(W, x, bvec, Tt4, out);
    k_main<<<256, 512, 0, stream>>>(W, Tt4, x, a, Oxy, out);
}